// Round 8
// baseline (369.390 us; speedup 1.0000x reference)
//
#include <hip/hip_runtime.h>
#include <hip/hip_bf16.h>
#include <math.h>

static constexpr int Bn = 2, Tn = 2048, Dn = 768, Hn = 8, Kn = 64, Vn = 96;

typedef __bf16 bf16x8 __attribute__((ext_vector_type(8)));
typedef __bf16 bf16x4v __attribute__((ext_vector_type(4)));
typedef float f32x4 __attribute__((ext_vector_type(4)));
typedef float f32x16 __attribute__((ext_vector_type(16)));

// fi = #{ i in [1,16] : pr^i - 1 <= a } = floor(log2(a+1) * 16/log2(2049)).
#define F0_SCALE 1.45445233f
#define LOG2E 1.44269504f
#define EXP2F(x) __builtin_amdgcn_exp2f(x)

// ---------------- cast x -> bf16 ----------------
__global__ __launch_bounds__(256) void castx_kernel(
    const float* __restrict__ x, __bf16* __restrict__ xb, int n4) {
    int i = blockIdx.x * 256 + threadIdx.x;
    const int stride = gridDim.x * 256;
    for (; i < n4; i += stride) {
        const float4 v = ((const float4*)x)[i];
        bf16x4v o; o[0] = (__bf16)v.x; o[1] = (__bf16)v.y; o[2] = (__bf16)v.z; o[3] = (__bf16)v.w;
        ((bf16x4v*)xb)[i] = o;
    }
}

// ---------------- transpose + cast: WT[n][k] = W[k][n], W is [K][N] f32 ----------------
__global__ __launch_bounds__(256) void transpose_kernel(
    const float* __restrict__ W, __bf16* __restrict__ WT, int Kd, int Nd) {
    __shared__ float tile[32][33];
    const int n0 = blockIdx.x * 32, k0 = blockIdx.y * 32;
    const int tx = threadIdx.x & 31, ty8 = threadIdx.x >> 5;
    for (int r = ty8; r < 32; r += 8)
        tile[r][tx] = W[(size_t)(k0 + r) * Nd + n0 + tx];
    __syncthreads();
    for (int r = ty8; r < 32; r += 8)
        WT[(size_t)(n0 + r) * Kd + k0 + tx] = (__bf16)tile[tx][r];
}

// ---------------- bf16 MFMA GEMM: C[128x128/block] = A[M][Kd] @ BT[N][Kd]^T ----------------
__global__ __launch_bounds__(256) void gemm_kernel(
    const __bf16* __restrict__ A, const __bf16* __restrict__ BT, int Kd, int mode,
    __bf16* __restrict__ qhb, __bf16* __restrict__ khb, __bf16* __restrict__ vtb,
    float* __restrict__ outp, const float* __restrict__ bo) {
    __shared__ __attribute__((aligned(16))) __bf16 smem[2][2][128 * 32];
    const int tid = threadIdx.x;
    const int w = tid >> 6, lane = tid & 63, g = lane >> 4, r16 = lane & 15;
    const int wr = w >> 1, wc = w & 1;
    const int rowBase = blockIdx.y * 128, colBase = blockIdx.x * 128;
    const int NK = Kd >> 5;

    const int srow0 = tid >> 2, part = tid & 3;
    const size_t Aoff0 = (size_t)(rowBase + srow0) * Kd + part * 8;
    const size_t Aoff1 = (size_t)(rowBase + 64 + srow0) * Kd + part * 8;
    const size_t Boff0 = (size_t)(colBase + srow0) * Kd + part * 8;
    const size_t Boff1 = (size_t)(colBase + 64 + srow0) * Kd + part * 8;
    const int sw = (srow0 & 7) << 4;
    const int woff0 = (srow0 * 64 + part * 16) ^ sw;
    const int woff1 = ((64 + srow0) * 64 + part * 16) ^ sw;

    int aoff[4], boff[4];
#pragma unroll
    for (int i = 0; i < 4; ++i) {
        const int rowA = wr * 64 + i * 16 + r16;
        aoff[i] = (rowA * 64 + g * 16) ^ ((rowA & 7) << 4);
        const int rowB = wc * 64 + i * 16 + r16;
        boff[i] = (rowB * 64 + g * 16) ^ ((rowB & 7) << 4);
    }

    f32x4 acc[4][4];
#pragma unroll
    for (int i = 0; i < 4; ++i)
#pragma unroll
        for (int j = 0; j < 4; ++j) acc[i][j] = (f32x4){0.f, 0.f, 0.f, 0.f};

    uint4 ar0 = *(const uint4*)(A + Aoff0);
    uint4 ar1 = *(const uint4*)(A + Aoff1);
    uint4 br0 = *(const uint4*)(BT + Boff0);
    uint4 br1 = *(const uint4*)(BT + Boff1);
    {
        char* Ab = (char*)&smem[0][0][0];
        char* Bb = (char*)&smem[0][1][0];
        *(uint4*)(Ab + woff0) = ar0; *(uint4*)(Ab + woff1) = ar1;
        *(uint4*)(Bb + woff0) = br0; *(uint4*)(Bb + woff1) = br1;
    }
    __syncthreads();
    int cur = 0;
    for (int kt = 0; kt < NK; ++kt) {
        if (kt + 1 < NK) {
            const size_t kb = (size_t)(kt + 1) * 32;
            ar0 = *(const uint4*)(A + Aoff0 + kb);
            ar1 = *(const uint4*)(A + Aoff1 + kb);
            br0 = *(const uint4*)(BT + Boff0 + kb);
            br1 = *(const uint4*)(BT + Boff1 + kb);
        }
        char* Ab = (char*)&smem[cur][0][0];
        char* Bb = (char*)&smem[cur][1][0];
        bf16x8 af[4], bfr[4];
#pragma unroll
        for (int i = 0; i < 4; ++i) af[i] = *(const bf16x8*)(Ab + aoff[i]);
#pragma unroll
        for (int j = 0; j < 4; ++j) bfr[j] = *(const bf16x8*)(Bb + boff[j]);
#pragma unroll
        for (int i = 0; i < 4; ++i)
#pragma unroll
            for (int j = 0; j < 4; ++j)
                acc[i][j] = __builtin_amdgcn_mfma_f32_16x16x32_bf16(af[i], bfr[j], acc[i][j], 0, 0, 0);
        if (kt + 1 < NK) {
            char* An = (char*)&smem[cur ^ 1][0][0];
            char* Bpn = (char*)&smem[cur ^ 1][1][0];
            *(uint4*)(An + woff0) = ar0; *(uint4*)(An + woff1) = ar1;
            *(uint4*)(Bpn + woff0) = br0; *(uint4*)(Bpn + woff1) = br1;
        }
        __syncthreads();
        cur ^= 1;
    }
    if (mode == 0) {
#pragma unroll
        for (int i = 0; i < 4; ++i)
#pragma unroll
            for (int j = 0; j < 4; ++j)
#pragma unroll
                for (int reg = 0; reg < 4; ++reg) {
                    const int row = rowBase + wr * 64 + i * 16 + 4 * g + reg;
                    const int col = colBase + wc * 64 + j * 16 + r16;
                    const float v = acc[i][j][reg];
                    const int b = row >> 11, t = row & (Tn - 1);
                    if (col < 512) {
                        qhb[(((size_t)b * Hn + (col >> 6)) * Tn + t) * Kn + (col & 63)] = (__bf16)(v * 0.125f);
                    } else if (col < 1024) {
                        const int c2 = col - 512;
                        // k pre-scaled by log2(e): logits in base-2 units
                        khb[(((size_t)b * Hn + (c2 >> 6)) * Tn + t) * Kn + (c2 & 63)] = (__bf16)(v * LOG2E);
                    } else {
                        const int c3 = col - 1024;
                        vtb[(((size_t)b * Hn + c3 / 96) * 96 + c3 % 96) * (size_t)Tn + t] = (__bf16)v;
                    }
                }
    } else {
#pragma unroll
        for (int i = 0; i < 4; ++i)
#pragma unroll
            for (int j = 0; j < 4; ++j)
#pragma unroll
                for (int reg = 0; reg < 4; ++reg) {
                    const int row = rowBase + wr * 64 + i * 16 + 4 * g + reg;
                    const int col = colBase + wc * 64 + j * 16 + r16;
                    outp[(size_t)row * Dn + col] = acc[i][j][reg] + bo[col];
                }
    }
}

// ---------------- rel-bias tables (x LOG2E) and content bias cb ----------------
__global__ __launch_bounds__(256) void bias_kernel(
    const __bf16* __restrict__ qhb, const __bf16* __restrict__ khb,
    const float* __restrict__ Wrk, const float* __restrict__ rwb,
    const float* __restrict__ rrb, float* __restrict__ S, __bf16* __restrict__ cbb) {
    __shared__ __attribute__((aligned(16))) float qs[32][68];
    __shared__ __attribute__((aligned(16))) float ks[32][68];
    __shared__ __attribute__((aligned(16))) float wr[32][68];
    __shared__ __attribute__((aligned(16))) float rr[64];
    __shared__ __attribute__((aligned(16))) float rw[64];
    __shared__ float us[32][36];
    const int tid = threadIdx.x;
    const int bh = blockIdx.y, h = bh & 7;
    const int t0 = blockIdx.x * 32;
    const int row = tid >> 3, g = tid & 7;
    {
        const bf16x8 qv = *(const bf16x8*)(qhb + ((size_t)bh * Tn + t0 + row) * Kn + g * 8);
        const bf16x8 kv = *(const bf16x8*)(khb + ((size_t)bh * Tn + t0 + row) * Kn + g * 8);
#pragma unroll
        for (int j = 0; j < 8; ++j) { qs[row][g * 8 + j] = (float)qv[j]; ks[row][g * 8 + j] = (float)kv[j]; }
        const float* wrp = Wrk + (size_t)row * (Hn * Kn) + h * Kn + g * 8;
        *(float4*)&wr[row][g * 8]     = *(const float4*)(wrp);
        *(float4*)&wr[row][g * 8 + 4] = *(const float4*)(wrp + 4);
    }
    if (tid < 64) { rr[tid] = rrb[h * Kn + tid]; rw[tid] = rwb[h * Kn + tid]; }
    __syncthreads();
#pragma unroll
    for (int ii = 0; ii < 4; ++ii) {
        const int i = g * 4 + ii;
        float acc = 0.f;
#pragma unroll
        for (int kk = 0; kk < 64; kk += 4) {
            const float4 q4 = *(const float4*)&qs[row][kk];
            const float4 r4 = *(const float4*)&rr[kk];
            const float4 w4 = *(const float4*)&wr[i][kk];
            acc += (q4.x + r4.x) * w4.x + (q4.y + r4.y) * w4.y +
                   (q4.z + r4.z) * w4.z + (q4.w + r4.w) * w4.w;
        }
        us[row][i] = acc;
    }
    float c = 0.f;
#pragma unroll
    for (int j = 0; j < 8; ++j) c += rw[g * 8 + j] * ks[row][g * 8 + j];
    c += __shfl_xor(c, 1, 8); c += __shfl_xor(c, 2, 8); c += __shfl_xor(c, 4, 8);
    if (g == 0) cbb[(size_t)bh * Tn + t0 + row] = (__bf16)c;   // already x LOG2E via khb
    __syncthreads();
    if (g == 0) {
        float* dst = S + ((size_t)bh * Tn + t0 + row) * 35;
        float s1 = 0.f, s2 = 0.f;
        dst[16] = 0.f; dst[33] = 0.f;
        for (int i = 15; i >= 0; --i) {
            s1 += us[row][i]; s2 += us[row][16 + i];
            dst[i] = (s1 + s2) * LOG2E;        // d > 0
            dst[17 + i] = (s1 - s2) * LOG2E;   // d < 0
        }
        dst[34] = s1 * LOG2E;                  // d == 0
    }
}

// ---------------- MFMA flash attention: swapped layout, 8-wave split-KV ----------------
// 1-D grid of 1024 blocks (XCD-swizzled), 512 threads = 8 waves.
// Block: 32 q-rows; wave w owns keys [w*256, w*256+256) = 8 tiles of 32.
// Inner loop identical to the round-6 (known-good, latency-measured) body.
__global__ __launch_bounds__(512, 8) void attn_kernel(
    const __bf16* __restrict__ qhb, const __bf16* __restrict__ khb,
    const __bf16* __restrict__ vtb, const float* __restrict__ Sg,
    const __bf16* __restrict__ cbb, __bf16* __restrict__ P) {
    __shared__ float SsL[32][35];
    __shared__ unsigned char dtab[4096];
    __shared__ float mlbuf[8][32][2];
    __shared__ float linv[32];
    __shared__ float obufA[32][97];
    __shared__ float obufB[32][97];
    const int tid = threadIdx.x;
    const int w = tid >> 6, lane = tid & 63;
    const int q = lane & 31, hi = lane >> 5;
    // XCD swizzle: linear id n -> (bh, t0) such that XCD (n%8) sees only 2 heads' K/V
    const int n = blockIdx.x;
    const int xcd = n & 7, slot = n >> 3;
    const int bh = xcd + 8 * (slot >> 6);
    const int t0 = (slot & 63) * 32;
    const int b = bh >> 3, h = bh & 7;

    for (int idx = tid; idx < 32 * 35; idx += 512)
        SsL[idx / 35][idx % 35] = Sg[((size_t)bh * Tn + t0 + idx / 35) * 35 + idx % 35];
    for (int idx = tid; idx < 4095; idx += 512) {
        const int d = idx - 2047;
        const int a = d < 0 ? -d : d;
        const int fi = (int)(__log2f((float)(a + 1)) * F0_SCALE);
        const int col = d > 0 ? fi : (d < 0 ? 17 + fi : 34);
        dtab[idx] = (unsigned char)(col * 4);
    }

    const __bf16* qrow = qhb + ((size_t)bh * Tn + t0 + q) * Kn + hi * 8;
    bf16x8 qf[4];
#pragma unroll
    for (int kt = 0; kt < 4; ++kt) qf[kt] = *(const bf16x8*)(qrow + kt * 16);
    bf16x8 qe = {};
    if (hi == 0) qe[0] = (__bf16)1.0f;

    f32x16 acc0 = {0.f}, acc1 = {0.f}, acc2 = {0.f};
    float m = -3.0e38f, l = 0.f;

    const size_t kbase = (size_t)bh * Tn * Kn;
    const size_t vbase = (size_t)bh * 96 * Tn;
    const size_t cbase = (size_t)bh * Tn;
    const int sBeg = w * (Tn / 8);
    const char* sslrow = (const char*)(&SsL[q][0]);

    __syncthreads();   // SsL + dtab ready

    for (int itile = 0; itile < Tn / 8 / 32; ++itile) {
        const int s0 = sBeg + itile * 32;
        // ---- QK^T (+cb) ----
        const __bf16* krow = khb + kbase + (size_t)(s0 + q) * Kn + hi * 8;
        f32x16 st = {0.f};
#pragma unroll
        for (int kt = 0; kt < 4; ++kt) {
            const bf16x8 kf = *(const bf16x8*)(krow + kt * 16);
            st = __builtin_amdgcn_mfma_f32_32x32x16_bf16(kf, qf[kt], st, 0, 0, 0);
        }
        {
            bf16x8 ke = {};
            if (hi == 0) ke[0] = cbb[cbase + s0 + q];
            st = __builtin_amdgcn_mfma_f32_32x32x16_bf16(ke, qe, st, 0, 0, 0);
        }
        // ---- rel bias via LDS tables + online softmax (base-2) ----
        const unsigned char* dp = dtab + (s0 - t0 - q + 2047);
        float p[16];
        float mt = -3.0e38f;
#pragma unroll
        for (int r = 0; r < 16; ++r) {
            const int kr = (r & 3) + 8 * (r >> 2) + 4 * hi;
            const int off = dp[kr];
            const float bias = *(const float*)(sslrow + off);
            p[r] = st[r] + bias;
            mt = fmaxf(mt, p[r]);
        }
        // defer-max: skip rescale unless some row's max grew past threshold
        if (!__all(mt - m <= 8.0f)) {
            mt = fmaxf(mt, __shfl_xor(mt, 32));
            const float mn = fmaxf(m, mt);
            const float sc = EXP2F(m - mn);
            m = mn;
            l *= sc;
            acc0 *= sc; acc1 *= sc; acc2 *= sc;
        }
        float ssum = 0.f;
#pragma unroll
        for (int r = 0; r < 16; ++r) { p[r] = EXP2F(p[r] - m); ssum += p[r]; }
        ssum += __shfl_xor(ssum, 32);
        l += ssum;
        // ---- pack P to bf16 B-fragments ----
        unsigned int c[8];
#pragma unroll
        for (int i = 0; i < 8; ++i) {
            union { __bf16 hh[2]; unsigned int u; } uu;
            uu.hh[0] = (__bf16)p[2 * i]; uu.hh[1] = (__bf16)p[2 * i + 1];
            c[i] = uu.u;
        }
        union { unsigned int u[4]; bf16x8 v; } B0, B1;
#if __has_builtin(__builtin_amdgcn_permlane32_swap)
        {
            auto r0 = __builtin_amdgcn_permlane32_swap((int)c[0], (int)c[2], false, false);
            auto r1 = __builtin_amdgcn_permlane32_swap((int)c[1], (int)c[3], false, false);
            auto r2 = __builtin_amdgcn_permlane32_swap((int)c[4], (int)c[6], false, false);
            auto r3 = __builtin_amdgcn_permlane32_swap((int)c[5], (int)c[7], false, false);
            B0.u[0] = (unsigned int)r0[0]; B0.u[2] = (unsigned int)r0[1];
            B0.u[1] = (unsigned int)r1[0]; B0.u[3] = (unsigned int)r1[1];
            B1.u[0] = (unsigned int)r2[0]; B1.u[2] = (unsigned int)r2[1];
            B1.u[1] = (unsigned int)r3[0]; B1.u[3] = (unsigned int)r3[1];
        }
#else
        {
            unsigned int x[8];
#pragma unroll
            for (int i = 0; i < 8; ++i) x[i] = __shfl_xor(c[i], 32);
            B0.u[0] = hi ? x[2] : c[0]; B0.u[1] = hi ? x[3] : c[1];
            B0.u[2] = hi ? c[2] : x[0]; B0.u[3] = hi ? c[3] : x[1];
            B1.u[0] = hi ? x[6] : c[4]; B1.u[1] = hi ? x[7] : c[5];
            B1.u[2] = hi ? c[6] : x[4]; B1.u[3] = hi ? c[7] : x[5];
        }
#endif
        // ---- PV: O^T += V^T * P^T ----
        {
            const __bf16* vrow = vtb + vbase + (size_t)(0 * 32 + q) * Tn + s0 + hi * 8;
            const bf16x8 vf0 = *(const bf16x8*)(vrow);
            const bf16x8 vf1 = *(const bf16x8*)(vrow + 16);
            acc0 = __builtin_amdgcn_mfma_f32_32x32x16_bf16(vf0, B0.v, acc0, 0, 0, 0);
            acc0 = __builtin_amdgcn_mfma_f32_32x32x16_bf16(vf1, B1.v, acc0, 0, 0, 0);
        }
        {
            const __bf16* vrow = vtb + vbase + (size_t)(1 * 32 + q) * Tn + s0 + hi * 8;
            const bf16x8 vf0 = *(const bf16x8*)(vrow);
            const bf16x8 vf1 = *(const bf16x8*)(vrow + 16);
            acc1 = __builtin_amdgcn_mfma_f32_32x32x16_bf16(vf0, B0.v, acc1, 0, 0, 0);
            acc1 = __builtin_amdgcn_mfma_f32_32x32x16_bf16(vf1, B1.v, acc1, 0, 0, 0);
        }
        {
            const __bf16* vrow = vtb + vbase + (size_t)(2 * 32 + q) * Tn + s0 + hi * 8;
            const bf16x8 vf0 = *(const bf16x8*)(vrow);
            const bf16x8 vf1 = *(const bf16x8*)(vrow + 16);
            acc2 = __builtin_amdgcn_mfma_f32_32x32x16_bf16(vf0, B0.v, acc2, 0, 0, 0);
            acc2 = __builtin_amdgcn_mfma_f32_32x32x16_bf16(vf1, B1.v, acc2, 0, 0, 0);
        }
    }

    // ---- flash combine across the 8 waves (base-2 weights), 4 phased rounds ----
    if (lane < 32) { mlbuf[w][q][0] = m; mlbuf[w][q][1] = l; }
    __syncthreads();
    float mstar = mlbuf[0][q][0];
#pragma unroll
    for (int ww = 1; ww < 8; ++ww) mstar = fmaxf(mstar, mlbuf[ww][q][0]);
    const float wme = EXP2F(m - mstar);
    if (w == 0 && lane < 32) {
        float ls = 0.f;
#pragma unroll
        for (int ww = 0; ww < 8; ++ww)
            ls += mlbuf[ww][q][1] * EXP2F(mlbuf[ww][q][0] - mstar);
        linv[q] = 1.f / ls;
    }
    float (*bufp)[97] = (w & 1) ? obufB : obufA;
    if (w < 2) {
#pragma unroll
        for (int r = 0; r < 16; ++r) {
            const int vr = (r & 3) + 8 * (r >> 2) + 4 * hi;
            bufp[q][vr] = acc0[r] * wme;
            bufp[q][32 + vr] = acc1[r] * wme;
            bufp[q][64 + vr] = acc2[r] * wme;
        }
    }
    __syncthreads();
#pragma unroll
    for (int phase = 1; phase < 4; ++phase) {
        if ((w >> 1) == phase) {
#pragma unroll
            for (int r = 0; r < 16; ++r) {
                const int vr = (r & 3) + 8 * (r >> 2) + 4 * hi;
                bufp[q][vr] += acc0[r] * wme;
                bufp[q][32 + vr] += acc1[r] * wme;
                bufp[q][64 + vr] += acc2[r] * wme;
            }
        }
        __syncthreads();
    }
    // ---- write O (bf16): 512 threads cover 32 rows x 96 cols, 6 each ----
    const int qo = tid >> 4, v0 = (tid & 15) * 6;
    const float li = linv[qo];
    __bf16* prow = P + ((size_t)b * Tn + t0 + qo) * Dn + h * Vn + v0;
#pragma unroll
    for (int j = 0; j < 6; j += 2) {
        const float u0 = (obufA[qo][v0 + j] + obufB[qo][v0 + j]) * li;
        const float u1 = (obufA[qo][v0 + j + 1] + obufB[qo][v0 + j + 1]) * li;
        union { __bf16 hh[2]; unsigned int u; } pk;
        pk.hh[0] = (__bf16)u0; pk.hh[1] = (__bf16)u1;
        *(unsigned int*)(prow + j) = pk.u;
    }
}

extern "C" void kernel_launch(void* const* d_in, const int* in_sizes, int n_in,
                              void* d_out, int out_size, void* d_ws, size_t ws_size,
                              hipStream_t stream) {
    (void)in_sizes; (void)n_in; (void)out_size; (void)ws_size;
    const float* x   = (const float*)d_in[0];
    const float* Wq  = (const float*)d_in[1];
    const float* Wk  = (const float*)d_in[2];
    const float* Wv  = (const float*)d_in[3];
    const float* Wrk = (const float*)d_in[4];
    const float* rwb = (const float*)d_in[5];
    const float* rrb = (const float*)d_in[6];
    const float* Wo  = (const float*)d_in[7];
    const float* bo  = (const float*)d_in[8];
    float* out = (float*)d_out;

    char* p = (char*)d_ws;
    auto alloc = [&](size_t bytes) { char* r = p; p += (bytes + 255) & ~(size_t)255; return r; };
    float*  Sb   = (float*)alloc((size_t)Bn * Hn * Tn * 35 * 4);
    __bf16* cbb  = (__bf16*)alloc((size_t)Bn * Hn * Tn * 2);
    __bf16* qhb  = (__bf16*)alloc((size_t)Bn * Hn * Tn * Kn * 2);
    __bf16* khb  = (__bf16*)alloc((size_t)Bn * Hn * Tn * Kn * 2);
    __bf16* vtb  = (__bf16*)alloc((size_t)Bn * Hn * 96 * Tn * 2);
    __bf16* Pmb  = (__bf16*)alloc((size_t)Bn * Tn * Dn * 2);
    __bf16* Xb   = (__bf16*)alloc((size_t)Bn * Tn * Dn * 2);
    __bf16* WT   = (__bf16*)alloc((size_t)1792 * 768 * 2);
    __bf16* WoT  = (__bf16*)alloc((size_t)768 * 768 * 2);

    castx_kernel<<<dim3(1536), 256, 0, stream>>>(x, Xb, Bn * Tn * Dn / 4);
    transpose_kernel<<<dim3(16, 24), 256, 0, stream>>>(Wq, WT, 768, 512);
    transpose_kernel<<<dim3(16, 24), 256, 0, stream>>>(Wk, WT + (size_t)512 * 768, 768, 512);
    transpose_kernel<<<dim3(24, 24), 256, 0, stream>>>(Wv, WT + (size_t)1024 * 768, 768, 768);
    transpose_kernel<<<dim3(24, 24), 256, 0, stream>>>(Wo, WoT, 768, 768);
    gemm_kernel<<<dim3(14, 32), 256, 0, stream>>>(Xb, WT, 768, 0, qhb, khb, vtb, nullptr, nullptr);
    bias_kernel<<<dim3(Tn / 32, Bn * Hn), 256, 0, stream>>>(qhb, khb, Wrk, rwb, rrb, Sb, cbb);
    attn_kernel<<<dim3(1024), 512, 0, stream>>>(qhb, khb, vtb, Sb, cbb, Pmb);
    gemm_kernel<<<dim3(6, 32), 256, 0, stream>>>(Pmb, WoT, 768, 1, nullptr, nullptr, nullptr, out, bo);
}

// Round 9
// 136.735 us; speedup vs baseline: 2.7015x; 2.7015x over previous
//
#include <hip/hip_runtime.h>
#include <hip/hip_bf16.h>
#include <math.h>

static constexpr int Bn = 2, Tn = 2048, Dn = 768, Hn = 8, Kn = 64, Vn = 96;

typedef __bf16 bf16x8 __attribute__((ext_vector_type(8)));
typedef __bf16 bf16x4v __attribute__((ext_vector_type(4)));
typedef float f32x4 __attribute__((ext_vector_type(4)));
typedef float f32x16 __attribute__((ext_vector_type(16)));

// fi = #{ i in [1,16] : pr^i - 1 <= a } = floor(log2(a+1) * 16/log2(2049)).
#define F0_SCALE 1.45445233f
#define LOG2E 1.44269504f
#define EXP2F(x) __builtin_amdgcn_exp2f(x)

// Packed fragment-major layouts (per 32-key tile, 64-lane coalesced chunks):
//   kpk[((bh*64 + it)*4 + kt)*512 + lane*8 + i]  = K[bh][it*32 + (lane&31)][kt*16 + (lane>>5)*8 + i]
//   vpk[((bh*64 + it)*6 + c )*512 + lane*8 + i]  = V[bh][it*32 + (c&1)*16 + (lane>>5)*8 + i][(c>>1)*32 + (lane&31)]

// ---------------- cast x -> bf16 ----------------
__global__ __launch_bounds__(256) void castx_kernel(
    const float* __restrict__ x, __bf16* __restrict__ xb, int n4) {
    int i = blockIdx.x * 256 + threadIdx.x;
    const int stride = gridDim.x * 256;
    for (; i < n4; i += stride) {
        const float4 v = ((const float4*)x)[i];
        bf16x4v o; o[0] = (__bf16)v.x; o[1] = (__bf16)v.y; o[2] = (__bf16)v.z; o[3] = (__bf16)v.w;
        ((bf16x4v*)xb)[i] = o;
    }
}

// ---------------- transpose + cast: WT[n][k] = W[k][n], W is [K][N] f32 ----------------
__global__ __launch_bounds__(256) void transpose_kernel(
    const float* __restrict__ W, __bf16* __restrict__ WT, int Kd, int Nd) {
    __shared__ float tile[32][33];
    const int n0 = blockIdx.x * 32, k0 = blockIdx.y * 32;
    const int tx = threadIdx.x & 31, ty8 = threadIdx.x >> 5;
    for (int r = ty8; r < 32; r += 8)
        tile[r][tx] = W[(size_t)(k0 + r) * Nd + n0 + tx];
    __syncthreads();
    for (int r = ty8; r < 32; r += 8)
        WT[(size_t)(n0 + r) * Kd + k0 + tx] = (__bf16)tile[tx][r];
}

// ---------------- bf16 MFMA GEMM: C[128x128/block] = A[M][Kd] @ BT[N][Kd]^T ----------------
__global__ __launch_bounds__(256) void gemm_kernel(
    const __bf16* __restrict__ A, const __bf16* __restrict__ BT, int Kd, int mode,
    __bf16* __restrict__ qhb, __bf16* __restrict__ kpk, __bf16* __restrict__ vpk,
    float* __restrict__ outp, const float* __restrict__ bo) {
    __shared__ __attribute__((aligned(16))) __bf16 smem[2][2][128 * 32];
    const int tid = threadIdx.x;
    const int w = tid >> 6, lane = tid & 63, g = lane >> 4, r16 = lane & 15;
    const int wr = w >> 1, wc = w & 1;
    const int rowBase = blockIdx.y * 128, colBase = blockIdx.x * 128;
    const int NK = Kd >> 5;

    const int srow0 = tid >> 2, part = tid & 3;
    const size_t Aoff0 = (size_t)(rowBase + srow0) * Kd + part * 8;
    const size_t Aoff1 = (size_t)(rowBase + 64 + srow0) * Kd + part * 8;
    const size_t Boff0 = (size_t)(colBase + srow0) * Kd + part * 8;
    const size_t Boff1 = (size_t)(colBase + 64 + srow0) * Kd + part * 8;
    const int sw = (srow0 & 7) << 4;
    const int woff0 = (srow0 * 64 + part * 16) ^ sw;
    const int woff1 = ((64 + srow0) * 64 + part * 16) ^ sw;

    int aoff[4], boff[4];
#pragma unroll
    for (int i = 0; i < 4; ++i) {
        const int rowA = wr * 64 + i * 16 + r16;
        aoff[i] = (rowA * 64 + g * 16) ^ ((rowA & 7) << 4);
        const int rowB = wc * 64 + i * 16 + r16;
        boff[i] = (rowB * 64 + g * 16) ^ ((rowB & 7) << 4);
    }

    f32x4 acc[4][4];
#pragma unroll
    for (int i = 0; i < 4; ++i)
#pragma unroll
        for (int j = 0; j < 4; ++j) acc[i][j] = (f32x4){0.f, 0.f, 0.f, 0.f};

    uint4 ar0 = *(const uint4*)(A + Aoff0);
    uint4 ar1 = *(const uint4*)(A + Aoff1);
    uint4 br0 = *(const uint4*)(BT + Boff0);
    uint4 br1 = *(const uint4*)(BT + Boff1);
    {
        char* Ab = (char*)&smem[0][0][0];
        char* Bb = (char*)&smem[0][1][0];
        *(uint4*)(Ab + woff0) = ar0; *(uint4*)(Ab + woff1) = ar1;
        *(uint4*)(Bb + woff0) = br0; *(uint4*)(Bb + woff1) = br1;
    }
    __syncthreads();
    int cur = 0;
    for (int kt = 0; kt < NK; ++kt) {
        if (kt + 1 < NK) {
            const size_t kb = (size_t)(kt + 1) * 32;
            ar0 = *(const uint4*)(A + Aoff0 + kb);
            ar1 = *(const uint4*)(A + Aoff1 + kb);
            br0 = *(const uint4*)(BT + Boff0 + kb);
            br1 = *(const uint4*)(BT + Boff1 + kb);
        }
        char* Ab = (char*)&smem[cur][0][0];
        char* Bb = (char*)&smem[cur][1][0];
        bf16x8 af[4], bfr[4];
#pragma unroll
        for (int i = 0; i < 4; ++i) af[i] = *(const bf16x8*)(Ab + aoff[i]);
#pragma unroll
        for (int j = 0; j < 4; ++j) bfr[j] = *(const bf16x8*)(Bb + boff[j]);
#pragma unroll
        for (int i = 0; i < 4; ++i)
#pragma unroll
            for (int j = 0; j < 4; ++j)
                acc[i][j] = __builtin_amdgcn_mfma_f32_16x16x32_bf16(af[i], bfr[j], acc[i][j], 0, 0, 0);
        if (kt + 1 < NK) {
            char* An = (char*)&smem[cur ^ 1][0][0];
            char* Bpn = (char*)&smem[cur ^ 1][1][0];
            *(uint4*)(An + woff0) = ar0; *(uint4*)(An + woff1) = ar1;
            *(uint4*)(Bpn + woff0) = br0; *(uint4*)(Bpn + woff1) = br1;
        }
        __syncthreads();
        cur ^= 1;
    }
    if (mode == 0) {
#pragma unroll
        for (int i = 0; i < 4; ++i)
#pragma unroll
            for (int j = 0; j < 4; ++j)
#pragma unroll
                for (int reg = 0; reg < 4; ++reg) {
                    const int row = rowBase + wr * 64 + i * 16 + 4 * g + reg;
                    const int col = colBase + wc * 64 + j * 16 + r16;
                    const float v = acc[i][j][reg];
                    const int b = row >> 11, t = row & (Tn - 1);
                    const int it = t >> 5;
                    if (col < 512) {
                        qhb[(((size_t)b * Hn + (col >> 6)) * Tn + t) * Kn + (col & 63)] = (__bf16)(v * 0.125f);
                    } else if (col < 1024) {
                        const int c2 = col - 512;
                        const int bh = b * Hn + (c2 >> 6), kk = c2 & 63;
                        const int ktc = kk >> 4, hi = (kk >> 3) & 1, ii = kk & 7;
                        // k pre-scaled by log2(e): logits in base-2 units
                        kpk[(size_t)(((bh * 64 + it) * 4 + ktc) * 64 + hi * 32 + (t & 31)) * 8 + ii] =
                            (__bf16)(v * LOG2E);
                    } else {
                        const int c3 = col - 1024;
                        const int bh = b * Hn + c3 / 96, vv = c3 % 96;
                        const int c = (vv >> 5) * 2 + ((t >> 4) & 1), hi = (t >> 3) & 1, ii = t & 7;
                        vpk[(size_t)(((bh * 64 + it) * 6 + c) * 64 + hi * 32 + (vv & 31)) * 8 + ii] =
                            (__bf16)v;
                    }
                }
    } else {
#pragma unroll
        for (int i = 0; i < 4; ++i)
#pragma unroll
            for (int j = 0; j < 4; ++j)
#pragma unroll
                for (int reg = 0; reg < 4; ++reg) {
                    const int row = rowBase + wr * 64 + i * 16 + 4 * g + reg;
                    const int col = colBase + wc * 64 + j * 16 + r16;
                    outp[(size_t)row * Dn + col] = acc[i][j][reg] + bo[col];
                }
    }
}

// ---------------- rel-bias tables (x LOG2E) and content bias cb ----------------
// K read from packed kpk layout; khb no longer exists.
__global__ __launch_bounds__(256) void bias_kernel(
    const __bf16* __restrict__ qhb, const __bf16* __restrict__ kpk,
    const float* __restrict__ Wrk, const float* __restrict__ rwb,
    const float* __restrict__ rrb, float* __restrict__ S, __bf16* __restrict__ cbb) {
    __shared__ __attribute__((aligned(16))) float qs[32][68];
    __shared__ __attribute__((aligned(16))) float ks[32][68];
    __shared__ __attribute__((aligned(16))) float wr[32][68];
    __shared__ __attribute__((aligned(16))) float rr[64];
    __shared__ __attribute__((aligned(16))) float rw[64];
    __shared__ float us[32][36];
    const int tid = threadIdx.x;
    const int bh = blockIdx.y, h = bh & 7;
    const int t0 = blockIdx.x * 32;
    const int row = tid >> 3, g = tid & 7;
    {
        const bf16x8 qv = *(const bf16x8*)(qhb + ((size_t)bh * Tn + t0 + row) * Kn + g * 8);
        // K fragment chunk: kk = g*8.. -> kt = g>>1, hi = g&1
        const bf16x8 kv = *(const bf16x8*)(kpk +
            (size_t)(((bh * 64 + (t0 >> 5)) * 4 + (g >> 1)) * 64 + (g & 1) * 32 + row) * 8);
#pragma unroll
        for (int j = 0; j < 8; ++j) { qs[row][g * 8 + j] = (float)qv[j]; ks[row][g * 8 + j] = (float)kv[j]; }
        const float* wrp = Wrk + (size_t)row * (Hn * Kn) + h * Kn + g * 8;
        *(float4*)&wr[row][g * 8]     = *(const float4*)(wrp);
        *(float4*)&wr[row][g * 8 + 4] = *(const float4*)(wrp + 4);
    }
    if (tid < 64) { rr[tid] = rrb[h * Kn + tid]; rw[tid] = rwb[h * Kn + tid]; }
    __syncthreads();
#pragma unroll
    for (int ii = 0; ii < 4; ++ii) {
        const int i = g * 4 + ii;
        float acc = 0.f;
#pragma unroll
        for (int kk = 0; kk < 64; kk += 4) {
            const float4 q4 = *(const float4*)&qs[row][kk];
            const float4 r4 = *(const float4*)&rr[kk];
            const float4 w4 = *(const float4*)&wr[i][kk];
            acc += (q4.x + r4.x) * w4.x + (q4.y + r4.y) * w4.y +
                   (q4.z + r4.z) * w4.z + (q4.w + r4.w) * w4.w;
        }
        us[row][i] = acc;
    }
    // cb = rw . k  (k already x LOG2E)
    float c = 0.f;
#pragma unroll
    for (int j = 0; j < 8; ++j) c += rw[g * 8 + j] * ks[row][g * 8 + j];
    c += __shfl_xor(c, 1, 8); c += __shfl_xor(c, 2, 8); c += __shfl_xor(c, 4, 8);
    if (g == 0) cbb[(size_t)bh * Tn + t0 + row] = (__bf16)c;
    __syncthreads();
    if (g == 0) {
        float* dst = S + ((size_t)bh * Tn + t0 + row) * 35;
        float s1 = 0.f, s2 = 0.f;
        dst[16] = 0.f; dst[33] = 0.f;
        for (int i = 15; i >= 0; --i) {
            s1 += us[row][i]; s2 += us[row][16 + i];
            dst[i] = (s1 + s2) * LOG2E;        // d > 0
            dst[17 + i] = (s1 - s2) * LOG2E;   // d < 0
        }
        dst[34] = s1 * LOG2E;                  // d == 0
    }
}

// ---------------- MFMA flash attention: swapped layout, split-KV, packed coalesced K/V ----------------
// 1-D grid of 1024 blocks, XCD-swizzled. Block: 32 q-rows, 4 waves; wave w owns 512 keys.
// All hot-loop global loads are base + lane*16B (one coalesced 1KB transaction each).
__global__ __launch_bounds__(256, 4) void attn_kernel(
    const __bf16* __restrict__ qhb, const __bf16* __restrict__ kpk,
    const __bf16* __restrict__ vpk, const float* __restrict__ Sg,
    const __bf16* __restrict__ cbb, __bf16* __restrict__ P) {
    __shared__ float SsL[32][35];
    __shared__ unsigned char dtab[4096];
    __shared__ float mlbuf[4][32][2];
    __shared__ float linv[32];
    __shared__ float obufA[32][97];
    __shared__ float obufB[32][97];
    const int tid = threadIdx.x;
    const int w = tid >> 6, lane = tid & 63;
    const int q = lane & 31, hi = lane >> 5;
    const int n = blockIdx.x;
    const int xcd = n & 7, slot = n >> 3;
    const int bh = xcd + 8 * (slot >> 6);
    const int t0 = (slot & 63) * 32;
    const int b = bh >> 3, h = bh & 7;

    for (int idx = tid; idx < 32 * 35; idx += 256)
        SsL[idx / 35][idx % 35] = Sg[((size_t)bh * Tn + t0 + idx / 35) * 35 + idx % 35];
    for (int idx = tid; idx < 4095; idx += 256) {
        const int d = idx - 2047;
        const int a = d < 0 ? -d : d;
        const int fi = (int)(__log2f((float)(a + 1)) * F0_SCALE);
        const int col = d > 0 ? fi : (d < 0 ? 17 + fi : 34);
        dtab[idx] = (unsigned char)(col * 4);
    }

    const __bf16* qrow = qhb + ((size_t)bh * Tn + t0 + q) * Kn + hi * 8;
    bf16x8 qf[4];
#pragma unroll
    for (int kt = 0; kt < 4; ++kt) qf[kt] = *(const bf16x8*)(qrow + kt * 16);
    bf16x8 qe = {};
    if (hi == 0) qe[0] = (__bf16)1.0f;

    f32x16 acc0 = {0.f}, acc1 = {0.f}, acc2 = {0.f};
    float m = -3.0e38f, l = 0.f;

    const size_t kp0 = (size_t)(bh * 64) * 4 * 512 + lane * 8;
    const size_t vp0 = (size_t)(bh * 64) * 6 * 512 + lane * 8;
    const size_t cbase = (size_t)bh * Tn;
    const int sBeg = w * (Tn / 4);
    const char* sslrow = (const char*)(&SsL[q][0]);

    __syncthreads();   // SsL + dtab ready

    for (int itile = 0; itile < Tn / 4 / 32; ++itile) {
        const int s0 = sBeg + itile * 32;
        const int tIdx = s0 >> 5;
        // ---- QK^T (+cb): 4 coalesced K-fragment loads ----
        const __bf16* kr = kpk + kp0 + (size_t)tIdx * (4 * 512);
        f32x16 st = {0.f};
#pragma unroll
        for (int kt = 0; kt < 4; ++kt) {
            const bf16x8 kf = *(const bf16x8*)(kr + kt * 512);
            st = __builtin_amdgcn_mfma_f32_32x32x16_bf16(kf, qf[kt], st, 0, 0, 0);
        }
        {
            bf16x8 ke = {};
            if (hi == 0) ke[0] = cbb[cbase + s0 + q];
            st = __builtin_amdgcn_mfma_f32_32x32x16_bf16(ke, qe, st, 0, 0, 0);
        }
        // ---- rel bias via LDS tables + online softmax (base-2) ----
        const unsigned char* dp = dtab + (s0 - t0 - q + 2047);
        float p[16];
        float mt = -3.0e38f;
#pragma unroll
        for (int r = 0; r < 16; ++r) {
            const int kr2 = (r & 3) + 8 * (r >> 2) + 4 * hi;
            const int off = dp[kr2];
            const float bias = *(const float*)(sslrow + off);
            p[r] = st[r] + bias;
            mt = fmaxf(mt, p[r]);
        }
        if (!__all(mt - m <= 8.0f)) {
            mt = fmaxf(mt, __shfl_xor(mt, 32));
            const float mn = fmaxf(m, mt);
            const float sc = EXP2F(m - mn);
            m = mn;
            l *= sc;
            acc0 *= sc; acc1 *= sc; acc2 *= sc;
        }
        float ssum = 0.f;
#pragma unroll
        for (int r = 0; r < 16; ++r) { p[r] = EXP2F(p[r] - m); ssum += p[r]; }
        ssum += __shfl_xor(ssum, 32);
        l += ssum;
        // ---- pack P to bf16 B-fragments ----
        unsigned int c[8];
#pragma unroll
        for (int i = 0; i < 8; ++i) {
            union { __bf16 hh[2]; unsigned int u; } uu;
            uu.hh[0] = (__bf16)p[2 * i]; uu.hh[1] = (__bf16)p[2 * i + 1];
            c[i] = uu.u;
        }
        union { unsigned int u[4]; bf16x8 v; } B0, B1;
#if __has_builtin(__builtin_amdgcn_permlane32_swap)
        {
            auto r0 = __builtin_amdgcn_permlane32_swap((int)c[0], (int)c[2], false, false);
            auto r1 = __builtin_amdgcn_permlane32_swap((int)c[1], (int)c[3], false, false);
            auto r2 = __builtin_amdgcn_permlane32_swap((int)c[4], (int)c[6], false, false);
            auto r3 = __builtin_amdgcn_permlane32_swap((int)c[5], (int)c[7], false, false);
            B0.u[0] = (unsigned int)r0[0]; B0.u[2] = (unsigned int)r0[1];
            B0.u[1] = (unsigned int)r1[0]; B0.u[3] = (unsigned int)r1[1];
            B1.u[0] = (unsigned int)r2[0]; B1.u[2] = (unsigned int)r2[1];
            B1.u[1] = (unsigned int)r3[0]; B1.u[3] = (unsigned int)r3[1];
        }
#else
        {
            unsigned int x[8];
#pragma unroll
            for (int i = 0; i < 8; ++i) x[i] = __shfl_xor(c[i], 32);
            B0.u[0] = hi ? x[2] : c[0]; B0.u[1] = hi ? x[3] : c[1];
            B0.u[2] = hi ? c[2] : x[0]; B0.u[3] = hi ? c[3] : x[1];
            B1.u[0] = hi ? x[6] : c[4]; B1.u[1] = hi ? x[7] : c[5];
            B1.u[2] = hi ? c[6] : x[4]; B1.u[3] = hi ? c[7] : x[5];
        }
#endif
        // ---- PV: 6 coalesced V-fragment loads ----
        const __bf16* vr = vpk + vp0 + (size_t)tIdx * (6 * 512);
        acc0 = __builtin_amdgcn_mfma_f32_32x32x16_bf16(*(const bf16x8*)(vr + 0 * 512), B0.v, acc0, 0, 0, 0);
        acc0 = __builtin_amdgcn_mfma_f32_32x32x16_bf16(*(const bf16x8*)(vr + 1 * 512), B1.v, acc0, 0, 0, 0);
        acc1 = __builtin_amdgcn_mfma_f32_32x32x16_bf16(*(const bf16x8*)(vr + 2 * 512), B0.v, acc1, 0, 0, 0);
        acc1 = __builtin_amdgcn_mfma_f32_32x32x16_bf16(*(const bf16x8*)(vr + 3 * 512), B1.v, acc1, 0, 0, 0);
        acc2 = __builtin_amdgcn_mfma_f32_32x32x16_bf16(*(const bf16x8*)(vr + 4 * 512), B0.v, acc2, 0, 0, 0);
        acc2 = __builtin_amdgcn_mfma_f32_32x32x16_bf16(*(const bf16x8*)(vr + 5 * 512), B1.v, acc2, 0, 0, 0);
    }

    // ---- flash combine across the 4 waves (base-2 weights) ----
    if (lane < 32) { mlbuf[w][q][0] = m; mlbuf[w][q][1] = l; }
    __syncthreads();
    const float mstar = fmaxf(fmaxf(mlbuf[0][q][0], mlbuf[1][q][0]),
                              fmaxf(mlbuf[2][q][0], mlbuf[3][q][0]));
    const float wme = EXP2F(m - mstar);
    if (w == 0 && lane < 32) {
        float ls = 0.f;
#pragma unroll
        for (int ww = 0; ww < 4; ++ww)
            ls += mlbuf[ww][q][1] * EXP2F(mlbuf[ww][q][0] - mstar);
        linv[q] = 1.f / ls;
    }
    float (*bufp)[97] = (w & 1) ? obufB : obufA;
    if (w < 2) {
#pragma unroll
        for (int r = 0; r < 16; ++r) {
            const int vr2 = (r & 3) + 8 * (r >> 2) + 4 * hi;
            bufp[q][vr2] = acc0[r] * wme;
            bufp[q][32 + vr2] = acc1[r] * wme;
            bufp[q][64 + vr2] = acc2[r] * wme;
        }
    }
    __syncthreads();
    if (w >= 2) {
#pragma unroll
        for (int r = 0; r < 16; ++r) {
            const int vr2 = (r & 3) + 8 * (r >> 2) + 4 * hi;
            bufp[q][vr2] += acc0[r] * wme;
            bufp[q][32 + vr2] += acc1[r] * wme;
            bufp[q][64 + vr2] += acc2[r] * wme;
        }
    }
    __syncthreads();
    const int qo = tid >> 3, v0 = (tid & 7) * 12;
    const float li = linv[qo];
    __bf16* prow = P + ((size_t)b * Tn + t0 + qo) * Dn + h * Vn + v0;
#pragma unroll
    for (int j = 0; j < 12; j += 2) {
        const float u0 = (obufA[qo][v0 + j] + obufB[qo][v0 + j]) * li;
        const float u1 = (obufA[qo][v0 + j + 1] + obufB[qo][v0 + j + 1]) * li;
        union { __bf16 hh[2]; unsigned int u; } pk;
        pk.hh[0] = (__bf16)u0; pk.hh[1] = (__bf16)u1;
        *(unsigned int*)(prow + j) = pk.u;
    }
}

extern "C" void kernel_launch(void* const* d_in, const int* in_sizes, int n_in,
                              void* d_out, int out_size, void* d_ws, size_t ws_size,
                              hipStream_t stream) {
    (void)in_sizes; (void)n_in; (void)out_size; (void)ws_size;
    const float* x   = (const float*)d_in[0];
    const float* Wq  = (const float*)d_in[1];
    const float* Wk  = (const float*)d_in[2];
    const float* Wv  = (const float*)d_in[3];
    const float* Wrk = (const float*)d_in[4];
    const float* rwb = (const float*)d_in[5];
    const float* rrb = (const float*)d_in[6];
    const float* Wo  = (const float*)d_in[7];
    const float* bo  = (const float*)d_in[8];
    float* out = (float*)d_out;

    char* p = (char*)d_ws;
    auto alloc = [&](size_t bytes) { char* r = p; p += (bytes + 255) & ~(size_t)255; return r; };
    float*  Sb   = (float*)alloc((size_t)Bn * Hn * Tn * 35 * 4);
    __bf16* cbb  = (__bf16*)alloc((size_t)Bn * Hn * Tn * 2);
    __bf16* qhb  = (__bf16*)alloc((size_t)Bn * Hn * Tn * Kn * 2);
    __bf16* kpk  = (__bf16*)alloc((size_t)Bn * Hn * 64 * 4 * 512 * 2);
    __bf16* vpk  = (__bf16*)alloc((size_t)Bn * Hn * 64 * 6 * 512 * 2);
    __bf16* Pmb  = (__bf16*)alloc((size_t)Bn * Tn * Dn * 2);
    __bf16* Xb   = (__bf16*)alloc((size_t)Bn * Tn * Dn * 2);
    __bf16* WT   = (__bf16*)alloc((size_t)1792 * 768 * 2);
    __bf16* WoT  = (__bf16*)alloc((size_t)768 * 768 * 2);

    castx_kernel<<<dim3(1536), 256, 0, stream>>>(x, Xb, Bn * Tn * Dn / 4);
    transpose_kernel<<<dim3(16, 24), 256, 0, stream>>>(Wq, WT, 768, 512);
    transpose_kernel<<<dim3(16, 24), 256, 0, stream>>>(Wk, WT + (size_t)512 * 768, 768, 512);
    transpose_kernel<<<dim3(24, 24), 256, 0, stream>>>(Wv, WT + (size_t)1024 * 768, 768, 768);
    transpose_kernel<<<dim3(24, 24), 256, 0, stream>>>(Wo, WoT, 768, 768);
    gemm_kernel<<<dim3(14, 32), 256, 0, stream>>>(Xb, WT, 768, 0, qhb, kpk, vpk, nullptr, nullptr);
    bias_kernel<<<dim3(Tn / 32, Bn * Hn), 256, 0, stream>>>(qhb, kpk, Wrk, rwb, rrb, Sb, cbb);
    attn_kernel<<<dim3(1024), 256, 0, stream>>>(qhb, kpk, vpk, Sb, cbb, Pmb);
    gemm_kernel<<<dim3(6, 32), 256, 0, stream>>>(Pmb, WoT, 768, 1, nullptr, nullptr, nullptr, out, bo);
}